// Round 7
// baseline (229.823 us; speedup 1.0000x reference)
//
#include <hip/hip_runtime.h>

// LightGCN propagation on MI355X (gfx950).
//   h_{k+1}[r,:] = sum_{e: row[e]==r} val[e] * h_k[col[e],:]   D=32
//   out = (x + h1 + h2 + h3) / 4
//
// Round 16: R15 post-mortem -- nontemporal was self-defeating: houtb (the
// NEXT layer's gather table) was written nt -> evicted from L2, every
// layer gathered cold; out lost inter-dispatch L2 hits. Reverted. The
// surviving diagnosis across R13/R14/R15: spmm is bound by random gathers
// into a 6.4 MB table that cannot fit the 4 MB per-XCD L2. Structural fix:
// FEATURE-SPLIT PASSES. SpMM is elementwise in feats, so each layer runs
// as two passes over 16-feat half-planes; the bf16 table is stored as two
// contiguous 3.2 MB planes. Pass fo touches only plane fo -> per-XCD
// working set 3.2 MB < 4 MB L2: residency is unconditional (no inter-block
// phase alignment needed, unlike R13's col-sort). Per edge a pass reads
// 32 B (2 lanes x 16 B); 4-lane group does 2 edges/iter; epilogue folds
// edge-parity with one shfl_xor(2). Request count/bytes across both passes
// identical to before. Costs: edges stream re-read (+12.8 MB/layer), 3
// extra launches, 8 shuffles/row.

#define NN 100000
#define NE 1600000
#define DD 32
#define CHUNK 4096
#define NCHUNK ((NE + CHUNK - 1) / CHUNK)   // 391
#define BROWS 128
#define NBKT ((NN + BROWS - 1) / BROWS)     // 782
#define LDSE 3072                           // LDS staging cap in bucket_sort
#define PLANE_U4 (NN * 2)                   // uint4s per 16-feat plane

__device__ __forceinline__ unsigned f2bf(float f) {
    unsigned u = __float_as_uint(f);
    return (u + 0x7fffu + ((u >> 16) & 1u)) >> 16;   // RNE
}

// ---- pass 1: per-chunk bucket histogram matrix H[c][b] (coalesced) -------

__global__ __launch_bounds__(1024) void hist_kernel(
    const int* __restrict__ row, int* __restrict__ H)
{
    __shared__ int cnt[NBKT];
    const int tid = threadIdx.x;
    const int start = blockIdx.x * CHUNK;
    const int n = min(CHUNK, NE - start);
    for (int k = tid; k < NBKT; k += 1024) cnt[k] = 0;
    __syncthreads();
    const int j = tid * 4;                       // 4 edges per thread
    if (j + 3 < n) {
        int4 r4 = *(const int4*)(row + start + j);
        atomicAdd(&cnt[r4.x >> 7], 1);
        atomicAdd(&cnt[r4.y >> 7], 1);
        atomicAdd(&cnt[r4.z >> 7], 1);
        atomicAdd(&cnt[r4.w >> 7], 1);
    } else {
        for (int k = j; k < n; k++) atomicAdd(&cnt[row[start + k] >> 7], 1);
    }
    __syncthreads();
    int* Hrow = H + (size_t)blockIdx.x * NBKT;
    for (int k = tid; k < NBKT; k += 1024) Hrow[k] = cnt[k];   // coalesced
}

// ---- pass 2a: wave-parallel per-bucket scan over chunks ------------------

__global__ __launch_bounds__(1024) void scan_tr_kernel(
    const int* __restrict__ H, int* __restrict__ Pt, int* __restrict__ tot)
{
    const int b = blockIdx.x * 16 + (threadIdx.x >> 6);
    if (b >= NBKT) return;
    const int lane = threadIdx.x & 63;
    int run = 0;
    #pragma unroll
    for (int c0 = 0; c0 < NCHUNK; c0 += 64) {
        int c = c0 + lane;
        int v = (c < NCHUNK) ? H[(size_t)c * NBKT + b] : 0;
        int x = v;
        #pragma unroll
        for (int off = 1; off < 64; off <<= 1) {
            int y = __shfl_up(x, off, 64);
            if (lane >= off) x += y;
        }
        if (c < NCHUNK) Pt[(size_t)b * NCHUNK + c] = run + x - v;  // exclusive
        run += __shfl(x, 63, 64);                 // wave total
    }
    if (lane == 0) tot[b] = run;
}

// ---- pass 2b: exclusive scan of 782 bucket totals ------------------------

__global__ __launch_bounds__(1024) void scan_buckets_kernel(
    const int* __restrict__ tot, int* __restrict__ bucketbase,
    int* __restrict__ row_ptr)
{
    const int tid = threadIdx.x;
    int v = (tid < NBKT) ? tot[tid] : 0;
    int lane = tid & 63, w = tid >> 6;          // 16 waves
    int x = v;
    #pragma unroll
    for (int off = 1; off < 64; off <<= 1) {
        int y = __shfl_up(x, off, 64);
        if (lane >= off) x += y;
    }
    __shared__ int wt[16];
    if (lane == 63) wt[w] = x;
    __syncthreads();
    if (w == 0 && lane < 16) {
        int y = wt[lane];
        #pragma unroll
        for (int off = 1; off < 16; off <<= 1) {
            int z = __shfl_up(y, off, 16);
            if ((lane & 15) >= off) y += z;
        }
        wt[lane] = y;                            // inclusive wave totals
    }
    __syncthreads();
    int wo = (w > 0) ? wt[w - 1] : 0;
    int excl = x + wo - v;
    if (tid < NBKT) bucketbase[tid] = excl;
    if (tid == NBKT) { bucketbase[NBKT] = NE; row_ptr[NN] = NE; }
}

// ---- pass 3: multisplit scatter, deterministic dest, LDS-staged stores ---
// record: ((row & 127) << 17) | col   (col < 2^17), val bits in .y

__global__ __launch_bounds__(1024) void scatter_kernel(
    const int* __restrict__ row, const int* __restrict__ col,
    const float* __restrict__ val, const int* __restrict__ bucketbase,
    const int* __restrict__ Pt, int2* __restrict__ tmp)
{
    __shared__ int cnt[NBKT];      // 3.1 KB
    __shared__ int lbase[NBKT];    // 3.1 KB  chunk-local exclusive scan
    __shared__ int gofs[NBKT];     // 3.1 KB  global base per bucket
    __shared__ int wt[16];
    __shared__ int2 recs[CHUNK];   // 32 KB   records in bucket order
    __shared__ int dest[CHUNK];    // 16 KB   global dst per sorted position
    const int tid = threadIdx.x;
    const int start = blockIdx.x * CHUNK;
    const int n = min(CHUNK, NE - start);
    for (int k = tid; k < NBKT; k += 1024) cnt[k] = 0;
    __syncthreads();

    int rrow[CHUNK / 1024], rcol[CHUNK / 1024], rank[CHUNK / 1024];
    float rval[CHUNK / 1024];
    #pragma unroll
    for (int k = 0; k < CHUNK / 1024; k++) {
        int j = k * 1024 + tid;
        if (j < n) {
            int r = row[start + j];
            rrow[k] = r;
            rcol[k] = col[start + j];
            rval[k] = val[start + j];
            rank[k] = atomicAdd(&cnt[r >> 7], 1);
        } else {
            rrow[k] = -1;
        }
    }
    __syncthreads();

    // block-level exclusive scan of cnt -> lbase; deterministic gofs
    int v = (tid < NBKT) ? cnt[tid] : 0;
    {
        int lane = tid & 63, w = tid >> 6;
        int x = v;
        #pragma unroll
        for (int off = 1; off < 64; off <<= 1) {
            int y = __shfl_up(x, off, 64);
            if (lane >= off) x += y;
        }
        if (lane == 63) wt[w] = x;
        __syncthreads();
        if (w == 0 && lane < 16) {
            int y = wt[lane];
            #pragma unroll
            for (int off = 1; off < 16; off <<= 1) {
                int z = __shfl_up(y, off, 16);
                if ((lane & 15) >= off) y += z;
            }
            wt[lane] = y;
        }
        __syncthreads();
        int excl = x + ((w > 0) ? wt[w - 1] : 0) - v;
        if (tid < NBKT) {
            lbase[tid] = excl;
            gofs[tid] = bucketbase[tid] + Pt[(size_t)tid * NCHUNK + blockIdx.x];
        }
    }
    __syncthreads();

    #pragma unroll
    for (int k = 0; k < CHUNK / 1024; k++) {
        if (rrow[k] >= 0) {
            int b = rrow[k] >> 7;
            int p = lbase[b] + rank[k];
            recs[p] = make_int2(((rrow[k] & 127) << 17) | rcol[k],
                                __float_as_int(rval[k]));
            dest[p] = gofs[b] + rank[k];
        }
    }
    __syncthreads();

    for (int p = tid; p < n; p += 1024)        // run-contiguous stores
        tmp[dest[p]] = recs[p];
}

// ---- pass 4: per-bucket row sort (wave-privatized counters) --------------

__global__ __launch_bounds__(512) void bucket_sort_kernel(
    const int* __restrict__ bucketbase, const int2* __restrict__ tmp,
    int* __restrict__ row_ptr, int2* __restrict__ edges)
{
    __shared__ int cntw[8][BROWS];   // 4 KB  per-wave counts
    __shared__ int curw[8][BROWS];   // 4 KB  per-wave cursors
    __shared__ int wt2[2];
    __shared__ int2 ed[LDSE];        // 24 KB staging
    const int tid = threadIdx.x;
    const int w   = tid >> 6;        // wave id 0..7
    const int b   = blockIdx.x;
    const int s   = bucketbase[b];
    const int e   = bucketbase[b + 1];
    const int tot = e - s;

    for (int k = tid; k < 8 * BROWS; k += 512) (&cntw[0][0])[k] = 0;
    __syncthreads();

    int2 rc[6];
    #pragma unroll
    for (int k = 0; k < 6; k++) {
        int j = s + k * 512 + tid;
        rc[k] = (j < e && j < s + LDSE) ? tmp[j] : make_int2(-1, 0);
        if (rc[k].x >= 0) atomicAdd(&cntw[w][rc[k].x >> 17], 1);
    }
    if (tot > LDSE)                                        // fallback count
        for (int j = s + LDSE + tid; j < e; j += 512)
            atomicAdd(&cntw[w][tmp[j].x >> 17], 1);
    __syncthreads();

    // deg per row, block-exclusive scan -> per-wave cursors + row_ptr
    int v = 0, x = 0;
    if (tid < BROWS) {
        int d = 0;
        #pragma unroll
        for (int ww = 0; ww < 8; ww++) d += cntw[ww][tid];
        v = d;
        int lane = tid & 63;
        x = v;
        #pragma unroll
        for (int off = 1; off < 64; off <<= 1) {
            int y = __shfl_up(x, off, 64);
            if (lane >= off) x += y;
        }
        if (lane == 63) wt2[tid >> 6] = x;
    }
    __syncthreads();
    if (tid < BROWS) {
        int excl = x + ((tid >> 6) ? wt2[0] : 0) - v;
        int r = b * BROWS + tid;
        if (r < NN) row_ptr[r] = s + excl;
        int run = excl;
        #pragma unroll
        for (int ww = 0; ww < 8; ww++) { curw[ww][tid] = run; run += cntw[ww][tid]; }
    }
    __syncthreads();

    if (tot <= LDSE) {
        #pragma unroll
        for (int k = 0; k < 6; k++) {
            if (rc[k].x >= 0) {
                int pos = atomicAdd(&curw[w][rc[k].x >> 17], 1);
                ed[pos] = make_int2(rc[k].x & 0x1FFFF, rc[k].y);
            }
        }
        __syncthreads();
        for (int k = tid; k < tot; k += 512)     // coalesced write-back
            edges[s + k] = ed[k];
    } else {
        // fallback (statistically unreachable: bucket > 3072)
        #pragma unroll
        for (int k = 0; k < 6; k++) {
            if (rc[k].x >= 0) {
                int pos = atomicAdd(&curw[w][rc[k].x >> 17], 1);
                edges[s + pos] = make_int2(rc[k].x & 0x1FFFF, rc[k].y);
            }
        }
        for (int j = s + LDSE + tid; j < e; j += 512) {
            int2 rec = tmp[j];
            int pos = atomicAdd(&curw[w][rec.x >> 17], 1);
            edges[s + pos] = make_int2(rec.x & 0x1FFFF, rec.y);
        }
    }
}

// ---- x -> bf16 PLANES: plane p holds feats [16p,16p+16) of all nodes ----
// word (u32) layout: hb[p*NN*8 + node*8 + wrd], wrd = feat-pair in plane.

__global__ __launch_bounds__(256) void cvt_kernel(
    const float2* __restrict__ xin2, unsigned* __restrict__ hb)
{
    int j = blockIdx.x * 256 + threadIdx.x;      // float2 index, NN*16
    if (j >= NN * 16) return;
    float2 f = xin2[j];
    int nd = j >> 4, ff = j & 15;                // ff = feat-pair 0..15
    hb[(ff >> 3) * (NN * 8) + nd * 8 + (ff & 7)] = f2bf(f.x) | (f2bf(f.y) << 16);
}

// ---- SpMM: one 16-feat plane per pass; 4-lane group = 2 edges/iter -------
// Lane t: tp = t>>1 selects edge parity, tc = t&1 selects 16B chunk of the
// 32 B plane-row. Plane = 3.2 MB -> resident in every XCD's 4 MB L2.
// Epilogue folds edge parity with shfl_xor(2); lanes t<2 write.
// MODE 0: houtp = bf16 plane of A x ; out chunk = x + A x
// MODE 1: houtp = bf16 plane of A h ; out chunk += A h
// MODE 2: out chunk = (out + A h) * 0.25

template <int MODE>
__global__ __launch_bounds__(256) void spmm_kernel(
    const int* __restrict__ row_ptr, const int2* __restrict__ edges,
    const uint4* __restrict__ hbp,               // gather plane (in)
    uint4* __restrict__ houtp,                   // next-table plane (out)
    const float4* __restrict__ xin4, float4* __restrict__ out4, int fo)
{
    const int g = blockIdx.x * 64 + (threadIdx.x >> 2);   // row
    if (g >= NN) return;
    const int t  = threadIdx.x & 3;
    const int tp = t >> 1;                       // edge parity
    const int tc = t & 1;                        // 16 B chunk of plane row
    const int s = row_ptr[g];
    const int e = row_ptr[g + 1];

    float acc[8] = {0.f, 0.f, 0.f, 0.f, 0.f, 0.f, 0.f, 0.f};

#define ACC8(W, V)                                                         \
    do {                                                                   \
        acc[0] += (V) * __uint_as_float((W).x << 16);                      \
        acc[1] += (V) * __uint_as_float((W).x & 0xffff0000u);              \
        acc[2] += (V) * __uint_as_float((W).y << 16);                      \
        acc[3] += (V) * __uint_as_float((W).y & 0xffff0000u);              \
        acc[4] += (V) * __uint_as_float((W).z << 16);                      \
        acc[5] += (V) * __uint_as_float((W).z & 0xffff0000u);              \
        acc[6] += (V) * __uint_as_float((W).w << 16);                      \
        acc[7] += (V) * __uint_as_float((W).w & 0xffff0000u);              \
    } while (0)

    int i = s;
    for (; i + 8 <= e; i += 8) {                 // 8 edges, 4 gathers/lane
        int2 r0 = edges[i + 0 + tp];
        int2 r1 = edges[i + 2 + tp];
        int2 r2 = edges[i + 4 + tp];
        int2 r3 = edges[i + 6 + tp];
        uint4 w0 = hbp[r0.x * 2 + tc];
        uint4 w1 = hbp[r1.x * 2 + tc];
        uint4 w2 = hbp[r2.x * 2 + tc];
        uint4 w3 = hbp[r3.x * 2 + tc];
        ACC8(w0, __int_as_float(r0.y)); ACC8(w1, __int_as_float(r1.y));
        ACC8(w2, __int_as_float(r2.y)); ACC8(w3, __int_as_float(r3.y));
    }
    for (; i + 2 <= e; i += 2) {
        int2 r0 = edges[i + tp];
        uint4 w0 = hbp[r0.x * 2 + tc];
        ACC8(w0, __int_as_float(r0.y));
    }
    if (i < e && tp == 0) {                      // odd tail edge
        int2 r0 = edges[i];
        uint4 w0 = hbp[r0.x * 2 + tc];
        ACC8(w0, __int_as_float(r0.y));
    }
#undef ACC8

    // fold edge parity: t0+=t2, t1+=t3
    #pragma unroll
    for (int k = 0; k < 8; k++) acc[k] += __shfl_xor(acc[k], 2, 64);

    if (t >= 2) return;
    // lane t in {0,1} owns feats [16*fo + 8t, 16*fo + 8t + 8)
    if (MODE == 0 || MODE == 1) {
        uint4 p;
        p.x = f2bf(acc[0]) | (f2bf(acc[1]) << 16);
        p.y = f2bf(acc[2]) | (f2bf(acc[3]) << 16);
        p.z = f2bf(acc[4]) | (f2bf(acc[5]) << 16);
        p.w = f2bf(acc[6]) | (f2bf(acc[7]) << 16);
        houtp[g * 2 + t] = p;
    }
    const int o = g * 8 + fo * 4 + t * 2;        // two float4s per lane
    float4 lo, hi;
    if (MODE == 0) {
        float4 x0 = xin4[o], x1 = xin4[o + 1];
        lo = make_float4(x0.x + acc[0], x0.y + acc[1], x0.z + acc[2], x0.w + acc[3]);
        hi = make_float4(x1.x + acc[4], x1.y + acc[5], x1.z + acc[6], x1.w + acc[7]);
    } else if (MODE == 1) {
        float4 o0 = out4[o], o1 = out4[o + 1];
        lo = make_float4(o0.x + acc[0], o0.y + acc[1], o0.z + acc[2], o0.w + acc[3]);
        hi = make_float4(o1.x + acc[4], o1.y + acc[5], o1.z + acc[6], o1.w + acc[7]);
    } else {
        float4 o0 = out4[o], o1 = out4[o + 1];
        lo = make_float4((o0.x + acc[0]) * 0.25f, (o0.y + acc[1]) * 0.25f,
                         (o0.z + acc[2]) * 0.25f, (o0.w + acc[3]) * 0.25f);
        hi = make_float4((o1.x + acc[4]) * 0.25f, (o1.y + acc[5]) * 0.25f,
                         (o1.z + acc[6]) * 0.25f, (o1.w + acc[7]) * 0.25f);
    }
    out4[o] = lo;
    out4[o + 1] = hi;
}

// ---- launch ---------------------------------------------------------------

extern "C" void kernel_launch(void* const* d_in, const int* in_sizes, int n_in,
                              void* d_out, int out_size, void* d_ws, size_t ws_size,
                              hipStream_t stream) {
    const int*   edge_row = (const int*)d_in[0];
    const int*   edge_col = (const int*)d_in[1];
    const float* edge_val = (const float*)d_in[2];
    const float* x        = (const float*)d_in[3];
    float* out = (float*)d_out;

    char* ws = (char*)d_ws;
    int*  H          = (int*)ws;   ws += (((size_t)NCHUNK * NBKT * 4) + 511) & ~511ull; // 1.22 MB
    int*  Pt         = (int*)ws;   ws += (((size_t)NBKT * NCHUNK * 4) + 511) & ~511ull; // 1.22 MB
    int*  tot        = (int*)ws;   ws += 4096;
    int*  bucketbase = (int*)ws;   ws += 4096;
    int*  row_ptr    = (int*)ws;   ws += ((size_t)(NN + 1) * 4 + 511) & ~511ull;
    int2* tmp        = (int2*)ws;  ws += (size_t)NE * 8 + 64;   // 12.8 MB
    int2* edges      = (int2*)ws;  ws += (size_t)NE * 8 + 64;   // 12.8 MB
    unsigned* hb0    = (unsigned*)ws;  ws += (size_t)NN * DD * 2;  // 6.4 MB (2 planes)
    unsigned* hb1    = (unsigned*)ws;  ws += (size_t)NN * DD * 2;  // 6.4 MB (2 planes)

    hist_kernel        <<<NCHUNK, 1024, 0, stream>>>(edge_row, H);
    scan_tr_kernel     <<<(NBKT + 15) / 16, 1024, 0, stream>>>(H, Pt, tot);
    scan_buckets_kernel<<<1, 1024, 0, stream>>>(tot, bucketbase, row_ptr);
    scatter_kernel     <<<NCHUNK, 1024, 0, stream>>>(edge_row, edge_col, edge_val,
                                                     bucketbase, Pt, tmp);
    bucket_sort_kernel <<<NBKT, 512, 0, stream>>>(bucketbase, tmp, row_ptr, edges);
    cvt_kernel         <<<(NN * 16 + 255) / 256, 256, 0, stream>>>(
                         (const float2*)x, hb0);

    const uint4* h0p0 = (const uint4*)hb0;
    const uint4* h0p1 = (const uint4*)hb0 + PLANE_U4;
    uint4*       h1p0 = (uint4*)hb1;
    uint4*       h1p1 = (uint4*)hb1 + PLANE_U4;

    dim3 sp_grid((NN + 63) / 64);   // 1563 blocks, 4 lanes/row, 64 rows/block
    // layer 1
    spmm_kernel<0><<<sp_grid, 256, 0, stream>>>(row_ptr, edges, h0p0, h1p0,
        (const float4*)x, (float4*)out, 0);
    spmm_kernel<0><<<sp_grid, 256, 0, stream>>>(row_ptr, edges, h0p1, h1p1,
        (const float4*)x, (float4*)out, 1);
    // layer 2
    spmm_kernel<1><<<sp_grid, 256, 0, stream>>>(row_ptr, edges, h1p0, (uint4*)h0p0,
        (const float4*)x, (float4*)out, 0);
    spmm_kernel<1><<<sp_grid, 256, 0, stream>>>(row_ptr, edges, h1p1, (uint4*)h0p1,
        (const float4*)x, (float4*)out, 1);
    // layer 3 (no next table)
    spmm_kernel<2><<<sp_grid, 256, 0, stream>>>(row_ptr, edges, h0p0, h1p0,
        (const float4*)x, (float4*)out, 0);
    spmm_kernel<2><<<sp_grid, 256, 0, stream>>>(row_ptr, edges, h0p1, h1p1,
        (const float4*)x, (float4*)out, 1);
}

// Round 9
// 186.911 us; speedup vs baseline: 1.2296x; 1.2296x over previous
//
#include <hip/hip_runtime.h>

// LightGCN propagation on MI355X (gfx950).
//   h_{k+1}[r,:] = sum_{e: row[e]==r} val[e] * h_k[col[e],:]   D=32
//   out = (x + h1 + h2 + h3) / 4
//
// Round 18: R17 bench died to container infra (failed twice) -- no
// measurement. Kernel re-audited (pipeline loop invariants, fused-cvt
// bounds) and resubmitted verbatim. Rationale recap: gather fetch is
// COMPULSORY (each of 8 non-coherent XCD L2s pulls the whole 6.4 MB table
// once/layer = 51.2 MB + 12.8 MB edges ~= the 64 MB measured in R10); all
// residency tricks (col-sort R13, rowperm R14, nontemporal R15,
// plane-split R16) were null/negative. spmm is latency-bound on its
// serial 2-round-trip batch loop. Fixes vs R12:
//  * spmm: software-pipelined edge loads (preload next 8-edge batch during
//    current gathers+FMA) -> edge-load round trip off the critical path;
//  * spmm: epilogue x/out reads hoisted to kernel start;
//  * cvt fused into bucket_sort (block b converts its 128 rows);
//  * bucket_sort keeps R14's wave-privatized counters.

#define NN 100000
#define NE 1600000
#define DD 32
#define CHUNK 4096
#define NCHUNK ((NE + CHUNK - 1) / CHUNK)   // 391
#define BROWS 128
#define NBKT ((NN + BROWS - 1) / BROWS)     // 782
#define LDSE 3072                           // LDS staging cap in bucket_sort

__device__ __forceinline__ unsigned f2bf(float f) {
    unsigned u = __float_as_uint(f);
    return (u + 0x7fffu + ((u >> 16) & 1u)) >> 16;   // RNE
}

// ---- pass 1: per-chunk bucket histogram matrix H[c][b] (coalesced) -------

__global__ __launch_bounds__(1024) void hist_kernel(
    const int* __restrict__ row, int* __restrict__ H)
{
    __shared__ int cnt[NBKT];
    const int tid = threadIdx.x;
    const int start = blockIdx.x * CHUNK;
    const int n = min(CHUNK, NE - start);
    for (int k = tid; k < NBKT; k += 1024) cnt[k] = 0;
    __syncthreads();
    const int j = tid * 4;                       // 4 edges per thread
    if (j + 3 < n) {
        int4 r4 = *(const int4*)(row + start + j);
        atomicAdd(&cnt[r4.x >> 7], 1);
        atomicAdd(&cnt[r4.y >> 7], 1);
        atomicAdd(&cnt[r4.z >> 7], 1);
        atomicAdd(&cnt[r4.w >> 7], 1);
    } else {
        for (int k = j; k < n; k++) atomicAdd(&cnt[row[start + k] >> 7], 1);
    }
    __syncthreads();
    int* Hrow = H + (size_t)blockIdx.x * NBKT;
    for (int k = tid; k < NBKT; k += 1024) Hrow[k] = cnt[k];   // coalesced
}

// ---- pass 2a: wave-parallel per-bucket scan over chunks ------------------

__global__ __launch_bounds__(1024) void scan_tr_kernel(
    const int* __restrict__ H, int* __restrict__ Pt, int* __restrict__ tot)
{
    const int b = blockIdx.x * 16 + (threadIdx.x >> 6);
    if (b >= NBKT) return;
    const int lane = threadIdx.x & 63;
    int run = 0;
    #pragma unroll
    for (int c0 = 0; c0 < NCHUNK; c0 += 64) {
        int c = c0 + lane;
        int v = (c < NCHUNK) ? H[(size_t)c * NBKT + b] : 0;
        int x = v;
        #pragma unroll
        for (int off = 1; off < 64; off <<= 1) {
            int y = __shfl_up(x, off, 64);
            if (lane >= off) x += y;
        }
        if (c < NCHUNK) Pt[(size_t)b * NCHUNK + c] = run + x - v;  // exclusive
        run += __shfl(x, 63, 64);                 // wave total
    }
    if (lane == 0) tot[b] = run;
}

// ---- pass 2b: exclusive scan of 782 bucket totals ------------------------

__global__ __launch_bounds__(1024) void scan_buckets_kernel(
    const int* __restrict__ tot, int* __restrict__ bucketbase,
    int* __restrict__ row_ptr)
{
    const int tid = threadIdx.x;
    int v = (tid < NBKT) ? tot[tid] : 0;
    int lane = tid & 63, w = tid >> 6;          // 16 waves
    int x = v;
    #pragma unroll
    for (int off = 1; off < 64; off <<= 1) {
        int y = __shfl_up(x, off, 64);
        if (lane >= off) x += y;
    }
    __shared__ int wt[16];
    if (lane == 63) wt[w] = x;
    __syncthreads();
    if (w == 0 && lane < 16) {
        int y = wt[lane];
        #pragma unroll
        for (int off = 1; off < 16; off <<= 1) {
            int z = __shfl_up(y, off, 16);
            if ((lane & 15) >= off) y += z;
        }
        wt[lane] = y;                            // inclusive wave totals
    }
    __syncthreads();
    int wo = (w > 0) ? wt[w - 1] : 0;
    int excl = x + wo - v;
    if (tid < NBKT) bucketbase[tid] = excl;
    if (tid == NBKT) { bucketbase[NBKT] = NE; row_ptr[NN] = NE; }
}

// ---- pass 3: multisplit scatter, deterministic dest, LDS-staged stores ---
// record: ((row & 127) << 17) | col   (col < 2^17), val bits in .y

__global__ __launch_bounds__(1024) void scatter_kernel(
    const int* __restrict__ row, const int* __restrict__ col,
    const float* __restrict__ val, const int* __restrict__ bucketbase,
    const int* __restrict__ Pt, int2* __restrict__ tmp)
{
    __shared__ int cnt[NBKT];      // 3.1 KB
    __shared__ int lbase[NBKT];    // 3.1 KB  chunk-local exclusive scan
    __shared__ int gofs[NBKT];     // 3.1 KB  global base per bucket
    __shared__ int wt[16];
    __shared__ int2 recs[CHUNK];   // 32 KB   records in bucket order
    __shared__ int dest[CHUNK];    // 16 KB   global dst per sorted position
    const int tid = threadIdx.x;
    const int start = blockIdx.x * CHUNK;
    const int n = min(CHUNK, NE - start);
    for (int k = tid; k < NBKT; k += 1024) cnt[k] = 0;
    __syncthreads();

    int rrow[CHUNK / 1024], rcol[CHUNK / 1024], rank[CHUNK / 1024];
    float rval[CHUNK / 1024];
    #pragma unroll
    for (int k = 0; k < CHUNK / 1024; k++) {
        int j = k * 1024 + tid;
        if (j < n) {
            int r = row[start + j];
            rrow[k] = r;
            rcol[k] = col[start + j];
            rval[k] = val[start + j];
            rank[k] = atomicAdd(&cnt[r >> 7], 1);
        } else {
            rrow[k] = -1;
        }
    }
    __syncthreads();

    // block-level exclusive scan of cnt -> lbase; deterministic gofs
    int v = (tid < NBKT) ? cnt[tid] : 0;
    {
        int lane = tid & 63, w = tid >> 6;
        int x = v;
        #pragma unroll
        for (int off = 1; off < 64; off <<= 1) {
            int y = __shfl_up(x, off, 64);
            if (lane >= off) x += y;
        }
        if (lane == 63) wt[w] = x;
        __syncthreads();
        if (w == 0 && lane < 16) {
            int y = wt[lane];
            #pragma unroll
            for (int off = 1; off < 16; off <<= 1) {
                int z = __shfl_up(y, off, 16);
                if ((lane & 15) >= off) y += z;
            }
            wt[lane] = y;
        }
        __syncthreads();
        int excl = x + ((w > 0) ? wt[w - 1] : 0) - v;
        if (tid < NBKT) {
            lbase[tid] = excl;
            gofs[tid] = bucketbase[tid] + Pt[(size_t)tid * NCHUNK + blockIdx.x];
        }
    }
    __syncthreads();

    #pragma unroll
    for (int k = 0; k < CHUNK / 1024; k++) {
        if (rrow[k] >= 0) {
            int b = rrow[k] >> 7;
            int p = lbase[b] + rank[k];
            recs[p] = make_int2(((rrow[k] & 127) << 17) | rcol[k],
                                __float_as_int(rval[k]));
            dest[p] = gofs[b] + rank[k];
        }
    }
    __syncthreads();

    for (int p = tid; p < n; p += 1024)        // run-contiguous stores
        tmp[dest[p]] = recs[p];
}

// ---- pass 4: per-bucket row sort (wave-privatized) + fused cvt -----------
// Block b also converts x rows [b*128, b*128+128) to the bf16 table
// (coalesced, hides in this kernel's latency slack; cvt kernel deleted).

__global__ __launch_bounds__(512) void bucket_sort_kernel(
    const int* __restrict__ bucketbase, const int2* __restrict__ tmp,
    int* __restrict__ row_ptr, int2* __restrict__ edges,
    const float2* __restrict__ xin2, unsigned* __restrict__ hb0)
{
    __shared__ int cntw[8][BROWS];   // 4 KB  per-wave counts
    __shared__ int curw[8][BROWS];   // 4 KB  per-wave cursors
    __shared__ int wt2[2];
    __shared__ int2 ed[LDSE];        // 24 KB staging
    const int tid = threadIdx.x;
    const int w   = tid >> 6;        // wave id 0..7
    const int b   = blockIdx.x;
    const int s   = bucketbase[b];
    const int e   = bucketbase[b + 1];
    const int tot = e - s;

    // fused cvt: this bucket's 128 rows = 2048 float2 words
    #pragma unroll
    for (int k = 0; k < 4; k++) {
        int j = b * 2048 + k * 512 + tid;
        if (j < NN * 16) {
            float2 f = xin2[j];
            hb0[j] = f2bf(f.x) | (f2bf(f.y) << 16);
        }
    }

    for (int k = tid; k < 8 * BROWS; k += 512) (&cntw[0][0])[k] = 0;
    __syncthreads();

    int2 rc[6];
    #pragma unroll
    for (int k = 0; k < 6; k++) {
        int j = s + k * 512 + tid;
        rc[k] = (j < e && j < s + LDSE) ? tmp[j] : make_int2(-1, 0);
        if (rc[k].x >= 0) atomicAdd(&cntw[w][rc[k].x >> 17], 1);
    }
    if (tot > LDSE)                                        // fallback count
        for (int j = s + LDSE + tid; j < e; j += 512)
            atomicAdd(&cntw[w][tmp[j].x >> 17], 1);
    __syncthreads();

    // deg per row, block-exclusive scan -> per-wave cursors + row_ptr
    int v = 0, x = 0;
    if (tid < BROWS) {
        int d = 0;
        #pragma unroll
        for (int ww = 0; ww < 8; ww++) d += cntw[ww][tid];
        v = d;
        int lane = tid & 63;
        x = v;
        #pragma unroll
        for (int off = 1; off < 64; off <<= 1) {
            int y = __shfl_up(x, off, 64);
            if (lane >= off) x += y;
        }
        if (lane == 63) wt2[tid >> 6] = x;
    }
    __syncthreads();
    if (tid < BROWS) {
        int excl = x + ((tid >> 6) ? wt2[0] : 0) - v;
        int r = b * BROWS + tid;
        if (r < NN) row_ptr[r] = s + excl;
        int run = excl;
        #pragma unroll
        for (int ww = 0; ww < 8; ww++) { curw[ww][tid] = run; run += cntw[ww][tid]; }
    }
    __syncthreads();

    if (tot <= LDSE) {
        #pragma unroll
        for (int k = 0; k < 6; k++) {
            if (rc[k].x >= 0) {
                int pos = atomicAdd(&curw[w][rc[k].x >> 17], 1);
                ed[pos] = make_int2(rc[k].x & 0x1FFFF, rc[k].y);
            }
        }
        __syncthreads();
        for (int k = tid; k < tot; k += 512)     // coalesced write-back
            edges[s + k] = ed[k];
    } else {
        // fallback (statistically unreachable: bucket > 3072)
        #pragma unroll
        for (int k = 0; k < 6; k++) {
            if (rc[k].x >= 0) {
                int pos = atomicAdd(&curw[w][rc[k].x >> 17], 1);
                edges[s + pos] = make_int2(rc[k].x & 0x1FFFF, rc[k].y);
            }
        }
        for (int j = s + LDSE + tid; j < e; j += 512) {
            int2 rec = tmp[j];
            int pos = atomicAdd(&curw[w][rec.x >> 17], 1);
            edges[s + pos] = make_int2(rec.x & 0x1FFFF, rec.y);
        }
    }
}

// ---- SpMM: 4-lane group per row, bf16 gather, software-pipelined ---------
// Lane t in [0,4) owns feats [8t, 8t+8) = one uint4 of the bf16 row.
// Next 8-edge batch is preloaded during current batch's gathers+FMA, so
// the edge-load round trip is off the critical path. Epilogue x/out reads
// hoisted to kernel start.
// MODE 0: houtb = bf16(A x)  ; out  = x + A x
// MODE 1: houtb = bf16(A h)  ; out += A h
// MODE 2: out = (out + A h) * 0.25

template <int MODE>
__global__ __launch_bounds__(256) void spmm_kernel(
    const int* __restrict__ row_ptr, const int2* __restrict__ edges,
    const uint4* __restrict__ hb4,               // bf16 table, 4 uint4/row
    uint4* __restrict__ houtb4,                  // next bf16 table
    const float4* __restrict__ xin4, float4* __restrict__ out4)
{
    const int g = blockIdx.x * 64 + (threadIdx.x >> 2);   // row
    if (g >= NN) return;
    const int t = threadIdx.x & 3;
    const int s = row_ptr[g];
    const int e = row_ptr[g + 1];
    const int o = g * 8 + t * 2;                 // epilogue float4 index

    // prefetch epilogue inputs (independent of the edge loop)
    float4 p0, p1;
    if (MODE == 0) { p0 = xin4[o]; p1 = xin4[o + 1]; }
    else           { p0 = out4[o]; p1 = out4[o + 1]; }

    float acc[8] = {0.f, 0.f, 0.f, 0.f, 0.f, 0.f, 0.f, 0.f};

#define ACC8(W, V)                                                         \
    do {                                                                   \
        acc[0] += (V) * __uint_as_float((W).x << 16);                      \
        acc[1] += (V) * __uint_as_float((W).x & 0xffff0000u);              \
        acc[2] += (V) * __uint_as_float((W).y << 16);                      \
        acc[3] += (V) * __uint_as_float((W).y & 0xffff0000u);              \
        acc[4] += (V) * __uint_as_float((W).z << 16);                      \
        acc[5] += (V) * __uint_as_float((W).z & 0xffff0000u);              \
        acc[6] += (V) * __uint_as_float((W).w << 16);                      \
        acc[7] += (V) * __uint_as_float((W).w & 0xffff0000u);              \
    } while (0)

    int2 a0, a1, a2, a3, a4, a5, a6, a7;
    int i = s;
    if (i + 8 <= e) {                            // preload first batch
        a0 = edges[i];     a1 = edges[i + 1];
        a2 = edges[i + 2]; a3 = edges[i + 3];
        a4 = edges[i + 4]; a5 = edges[i + 5];
        a6 = edges[i + 6]; a7 = edges[i + 7];
    }
    for (; i + 16 <= e; i += 8) {                // pipelined main loop
        uint4 w0 = hb4[a0.x * 4 + t];
        uint4 w1 = hb4[a1.x * 4 + t];
        uint4 w2 = hb4[a2.x * 4 + t];
        uint4 w3 = hb4[a3.x * 4 + t];
        uint4 w4 = hb4[a4.x * 4 + t];
        uint4 w5 = hb4[a5.x * 4 + t];
        uint4 w6 = hb4[a6.x * 4 + t];
        uint4 w7 = hb4[a7.x * 4 + t];
        int2 b0 = edges[i + 8];  int2 b1 = edges[i + 9];
        int2 b2 = edges[i + 10]; int2 b3 = edges[i + 11];
        int2 b4 = edges[i + 12]; int2 b5 = edges[i + 13];
        int2 b6 = edges[i + 14]; int2 b7 = edges[i + 15];
        ACC8(w0, __int_as_float(a0.y)); ACC8(w1, __int_as_float(a1.y));
        ACC8(w2, __int_as_float(a2.y)); ACC8(w3, __int_as_float(a3.y));
        ACC8(w4, __int_as_float(a4.y)); ACC8(w5, __int_as_float(a5.y));
        ACC8(w6, __int_as_float(a6.y)); ACC8(w7, __int_as_float(a7.y));
        a0 = b0; a1 = b1; a2 = b2; a3 = b3;
        a4 = b4; a5 = b5; a6 = b6; a7 = b7;
    }
    if (i + 8 <= e) {                            // last preloaded batch
        uint4 w0 = hb4[a0.x * 4 + t];
        uint4 w1 = hb4[a1.x * 4 + t];
        uint4 w2 = hb4[a2.x * 4 + t];
        uint4 w3 = hb4[a3.x * 4 + t];
        uint4 w4 = hb4[a4.x * 4 + t];
        uint4 w5 = hb4[a5.x * 4 + t];
        uint4 w6 = hb4[a6.x * 4 + t];
        uint4 w7 = hb4[a7.x * 4 + t];
        ACC8(w0, __int_as_float(a0.y)); ACC8(w1, __int_as_float(a1.y));
        ACC8(w2, __int_as_float(a2.y)); ACC8(w3, __int_as_float(a3.y));
        ACC8(w4, __int_as_float(a4.y)); ACC8(w5, __int_as_float(a5.y));
        ACC8(w6, __int_as_float(a6.y)); ACC8(w7, __int_as_float(a7.y));
        i += 8;
    }
    for (; i + 4 <= e; i += 4) {
        int2 c0 = edges[i];
        int2 c1 = edges[i + 1];
        int2 c2 = edges[i + 2];
        int2 c3 = edges[i + 3];
        uint4 w0 = hb4[c0.x * 4 + t];
        uint4 w1 = hb4[c1.x * 4 + t];
        uint4 w2 = hb4[c2.x * 4 + t];
        uint4 w3 = hb4[c3.x * 4 + t];
        ACC8(w0, __int_as_float(c0.y)); ACC8(w1, __int_as_float(c1.y));
        ACC8(w2, __int_as_float(c2.y)); ACC8(w3, __int_as_float(c3.y));
    }
    for (; i < e; ++i) {
        int2 c0 = edges[i];
        uint4 w0 = hb4[c0.x * 4 + t];
        ACC8(w0, __int_as_float(c0.y));
    }
#undef ACC8

    // epilogue: lane owns feats [8t, 8t+8)
    if (MODE == 0 || MODE == 1) {
        uint4 p;
        p.x = f2bf(acc[0]) | (f2bf(acc[1]) << 16);
        p.y = f2bf(acc[2]) | (f2bf(acc[3]) << 16);
        p.z = f2bf(acc[4]) | (f2bf(acc[5]) << 16);
        p.w = f2bf(acc[6]) | (f2bf(acc[7]) << 16);
        houtb4[g * 4 + t] = p;
    }
    float4 lo, hi;
    if (MODE == 0 || MODE == 1) {
        lo = make_float4(p0.x + acc[0], p0.y + acc[1], p0.z + acc[2], p0.w + acc[3]);
        hi = make_float4(p1.x + acc[4], p1.y + acc[5], p1.z + acc[6], p1.w + acc[7]);
    } else {
        lo = make_float4((p0.x + acc[0]) * 0.25f, (p0.y + acc[1]) * 0.25f,
                         (p0.z + acc[2]) * 0.25f, (p0.w + acc[3]) * 0.25f);
        hi = make_float4((p1.x + acc[4]) * 0.25f, (p1.y + acc[5]) * 0.25f,
                         (p1.z + acc[6]) * 0.25f, (p1.w + acc[7]) * 0.25f);
    }
    out4[o] = lo;
    out4[o + 1] = hi;
}

// ---- launch ---------------------------------------------------------------

extern "C" void kernel_launch(void* const* d_in, const int* in_sizes, int n_in,
                              void* d_out, int out_size, void* d_ws, size_t ws_size,
                              hipStream_t stream) {
    const int*   edge_row = (const int*)d_in[0];
    const int*   edge_col = (const int*)d_in[1];
    const float* edge_val = (const float*)d_in[2];
    const float* x        = (const float*)d_in[3];
    float* out = (float*)d_out;

    char* ws = (char*)d_ws;
    int*  H          = (int*)ws;   ws += (((size_t)NCHUNK * NBKT * 4) + 511) & ~511ull; // 1.22 MB
    int*  Pt         = (int*)ws;   ws += (((size_t)NBKT * NCHUNK * 4) + 511) & ~511ull; // 1.22 MB
    int*  tot        = (int*)ws;   ws += 4096;
    int*  bucketbase = (int*)ws;   ws += 4096;
    int*  row_ptr    = (int*)ws;   ws += ((size_t)(NN + 1) * 4 + 511) & ~511ull;
    int2* tmp        = (int2*)ws;  ws += (size_t)NE * 8 + 64;   // 12.8 MB
    int2* edges      = (int2*)ws;  ws += (size_t)NE * 8 + 64;   // 12.8 MB
    unsigned* hb0    = (unsigned*)ws;  ws += (size_t)NN * DD * 2;  // 6.4 MB bf16
    unsigned* hb1    = (unsigned*)ws;  ws += (size_t)NN * DD * 2;  // 6.4 MB bf16

    hist_kernel        <<<NCHUNK, 1024, 0, stream>>>(edge_row, H);
    scan_tr_kernel     <<<(NBKT + 15) / 16, 1024, 0, stream>>>(H, Pt, tot);
    scan_buckets_kernel<<<1, 1024, 0, stream>>>(tot, bucketbase, row_ptr);
    scatter_kernel     <<<NCHUNK, 1024, 0, stream>>>(edge_row, edge_col, edge_val,
                                                     bucketbase, Pt, tmp);
    bucket_sort_kernel <<<NBKT, 512, 0, stream>>>(bucketbase, tmp, row_ptr, edges,
                                                  (const float2*)x, hb0);

    dim3 sp_grid((NN + 63) / 64);   // 1563 blocks, 4 lanes/row, 64 rows/block
    spmm_kernel<0><<<sp_grid, 256, 0, stream>>>(row_ptr, edges,
        (const uint4*)hb0, (uint4*)hb1, (const float4*)x, (float4*)out);
    spmm_kernel<1><<<sp_grid, 256, 0, stream>>>(row_ptr, edges,
        (const uint4*)hb1, (uint4*)hb0, (const float4*)x, (float4*)out);
    spmm_kernel<2><<<sp_grid, 256, 0, stream>>>(row_ptr, edges,
        (const uint4*)hb0, (uint4*)hb1, (const float4*)x, (float4*)out);
}

// Round 10
// 180.498 us; speedup vs baseline: 1.2733x; 1.0355x over previous
//
#include <hip/hip_runtime.h>
#include <hip/hip_fp16.h>

// LightGCN propagation on MI355X (gfx950).
//   h_{k+1}[r,:] = sum_{e: row[e]==r} val[e] * h_k[col[e],:]   D=32
//   out = (x + h1 + h2 + h3) / 4
//
// Round 19: R18 confirmed (186.9 us, best-ever): spmm responds to latency
// pipelining; the structural cost is L2/L3 traffic (51.2 MB compulsory
// table fill + streams at ~2.5-3 TB/s effective random-line rate). This
// round cuts stream BYTES: edge record compressed 8 B -> 4 B.
//   col < 2^17, val in [0,1) -> sign bit is 0 -> fp16 e5m10 sans sign =
//   15 bits (rel err 2^-11 ~ 0.05%, negligible vs bf16 table's 0.4%).
//   edge u32 = (col << 15) | fp16bits(val).
// Halves: bucket_sort edges write (-6.4 MB), spmm edges stream x3 layers
// (-19.2 MB), edge line requests, and bucket_sort LDS staging (32->20 KB
// -> more resident blocks). tmp stays 8 B (row bits needed pre-sort);
// val->fp16 converted once in bucket_sort. spmm keeps R18's pipeline
// structure verbatim (preload-next-batch + hoisted epilogue inputs).

#define NN 100000
#define NE 1600000
#define DD 32
#define CHUNK 4096
#define NCHUNK ((NE + CHUNK - 1) / CHUNK)   // 391
#define BROWS 128
#define NBKT ((NN + BROWS - 1) / BROWS)     // 782
#define LDSE 3072                           // LDS staging cap in bucket_sort

__device__ __forceinline__ unsigned f2bf(float f) {
    unsigned u = __float_as_uint(f);
    return (u + 0x7fffu + ((u >> 16) & 1u)) >> 16;   // RNE
}

// val (>=0) -> 15-bit fp16 payload
__device__ __forceinline__ unsigned f2h15(float v) {
    return (unsigned)__half_as_ushort(__float2half(v)) & 0x7fffu;
}
// 15-bit fp16 payload -> float
__device__ __forceinline__ float h152f(unsigned u) {
    return __half2float(__ushort_as_half((unsigned short)(u & 0x7fffu)));
}

// ---- pass 1: per-chunk bucket histogram matrix H[c][b] (coalesced) -------

__global__ __launch_bounds__(1024) void hist_kernel(
    const int* __restrict__ row, int* __restrict__ H)
{
    __shared__ int cnt[NBKT];
    const int tid = threadIdx.x;
    const int start = blockIdx.x * CHUNK;
    const int n = min(CHUNK, NE - start);
    for (int k = tid; k < NBKT; k += 1024) cnt[k] = 0;
    __syncthreads();
    const int j = tid * 4;                       // 4 edges per thread
    if (j + 3 < n) {
        int4 r4 = *(const int4*)(row + start + j);
        atomicAdd(&cnt[r4.x >> 7], 1);
        atomicAdd(&cnt[r4.y >> 7], 1);
        atomicAdd(&cnt[r4.z >> 7], 1);
        atomicAdd(&cnt[r4.w >> 7], 1);
    } else {
        for (int k = j; k < n; k++) atomicAdd(&cnt[row[start + k] >> 7], 1);
    }
    __syncthreads();
    int* Hrow = H + (size_t)blockIdx.x * NBKT;
    for (int k = tid; k < NBKT; k += 1024) Hrow[k] = cnt[k];   // coalesced
}

// ---- pass 2a: wave-parallel per-bucket scan over chunks ------------------

__global__ __launch_bounds__(1024) void scan_tr_kernel(
    const int* __restrict__ H, int* __restrict__ Pt, int* __restrict__ tot)
{
    const int b = blockIdx.x * 16 + (threadIdx.x >> 6);
    if (b >= NBKT) return;
    const int lane = threadIdx.x & 63;
    int run = 0;
    #pragma unroll
    for (int c0 = 0; c0 < NCHUNK; c0 += 64) {
        int c = c0 + lane;
        int v = (c < NCHUNK) ? H[(size_t)c * NBKT + b] : 0;
        int x = v;
        #pragma unroll
        for (int off = 1; off < 64; off <<= 1) {
            int y = __shfl_up(x, off, 64);
            if (lane >= off) x += y;
        }
        if (c < NCHUNK) Pt[(size_t)b * NCHUNK + c] = run + x - v;  // exclusive
        run += __shfl(x, 63, 64);                 // wave total
    }
    if (lane == 0) tot[b] = run;
}

// ---- pass 2b: exclusive scan of 782 bucket totals ------------------------

__global__ __launch_bounds__(1024) void scan_buckets_kernel(
    const int* __restrict__ tot, int* __restrict__ bucketbase,
    int* __restrict__ row_ptr)
{
    const int tid = threadIdx.x;
    int v = (tid < NBKT) ? tot[tid] : 0;
    int lane = tid & 63, w = tid >> 6;          // 16 waves
    int x = v;
    #pragma unroll
    for (int off = 1; off < 64; off <<= 1) {
        int y = __shfl_up(x, off, 64);
        if (lane >= off) x += y;
    }
    __shared__ int wt[16];
    if (lane == 63) wt[w] = x;
    __syncthreads();
    if (w == 0 && lane < 16) {
        int y = wt[lane];
        #pragma unroll
        for (int off = 1; off < 16; off <<= 1) {
            int z = __shfl_up(y, off, 16);
            if ((lane & 15) >= off) y += z;
        }
        wt[lane] = y;                            // inclusive wave totals
    }
    __syncthreads();
    int wo = (w > 0) ? wt[w - 1] : 0;
    int excl = x + wo - v;
    if (tid < NBKT) bucketbase[tid] = excl;
    if (tid == NBKT) { bucketbase[NBKT] = NE; row_ptr[NN] = NE; }
}

// ---- pass 3: multisplit scatter, deterministic dest, LDS-staged stores ---
// record: ((row & 127) << 17) | col   (col < 2^17), val bits in .y

__global__ __launch_bounds__(1024) void scatter_kernel(
    const int* __restrict__ row, const int* __restrict__ col,
    const float* __restrict__ val, const int* __restrict__ bucketbase,
    const int* __restrict__ Pt, int2* __restrict__ tmp)
{
    __shared__ int cnt[NBKT];      // 3.1 KB
    __shared__ int lbase[NBKT];    // 3.1 KB  chunk-local exclusive scan
    __shared__ int gofs[NBKT];     // 3.1 KB  global base per bucket
    __shared__ int wt[16];
    __shared__ int2 recs[CHUNK];   // 32 KB   records in bucket order
    __shared__ int dest[CHUNK];    // 16 KB   global dst per sorted position
    const int tid = threadIdx.x;
    const int start = blockIdx.x * CHUNK;
    const int n = min(CHUNK, NE - start);
    for (int k = tid; k < NBKT; k += 1024) cnt[k] = 0;
    __syncthreads();

    int rrow[CHUNK / 1024], rcol[CHUNK / 1024], rank[CHUNK / 1024];
    float rval[CHUNK / 1024];
    #pragma unroll
    for (int k = 0; k < CHUNK / 1024; k++) {
        int j = k * 1024 + tid;
        if (j < n) {
            int r = row[start + j];
            rrow[k] = r;
            rcol[k] = col[start + j];
            rval[k] = val[start + j];
            rank[k] = atomicAdd(&cnt[r >> 7], 1);
        } else {
            rrow[k] = -1;
        }
    }
    __syncthreads();

    // block-level exclusive scan of cnt -> lbase; deterministic gofs
    int v = (tid < NBKT) ? cnt[tid] : 0;
    {
        int lane = tid & 63, w = tid >> 6;
        int x = v;
        #pragma unroll
        for (int off = 1; off < 64; off <<= 1) {
            int y = __shfl_up(x, off, 64);
            if (lane >= off) x += y;
        }
        if (lane == 63) wt[w] = x;
        __syncthreads();
        if (w == 0 && lane < 16) {
            int y = wt[lane];
            #pragma unroll
            for (int off = 1; off < 16; off <<= 1) {
                int z = __shfl_up(y, off, 16);
                if ((lane & 15) >= off) y += z;
            }
            wt[lane] = y;
        }
        __syncthreads();
        int excl = x + ((w > 0) ? wt[w - 1] : 0) - v;
        if (tid < NBKT) {
            lbase[tid] = excl;
            gofs[tid] = bucketbase[tid] + Pt[(size_t)tid * NCHUNK + blockIdx.x];
        }
    }
    __syncthreads();

    #pragma unroll
    for (int k = 0; k < CHUNK / 1024; k++) {
        if (rrow[k] >= 0) {
            int b = rrow[k] >> 7;
            int p = lbase[b] + rank[k];
            recs[p] = make_int2(((rrow[k] & 127) << 17) | rcol[k],
                                __float_as_int(rval[k]));
            dest[p] = gofs[b] + rank[k];
        }
    }
    __syncthreads();

    for (int p = tid; p < n; p += 1024)        // run-contiguous stores
        tmp[dest[p]] = recs[p];
}

// ---- pass 4: per-bucket row sort (wave-privatized) + fused cvt -----------
// Emits COMPRESSED edges: u32 = (col << 15) | fp16bits(val)  (val >= 0).
// Block b also converts x rows [b*128, b*128+128) to the bf16 table.

__global__ __launch_bounds__(512) void bucket_sort_kernel(
    const int* __restrict__ bucketbase, const int2* __restrict__ tmp,
    int* __restrict__ row_ptr, unsigned* __restrict__ edges,
    const float2* __restrict__ xin2, unsigned* __restrict__ hb0)
{
    __shared__ int cntw[8][BROWS];   // 4 KB  per-wave counts
    __shared__ int curw[8][BROWS];   // 4 KB  per-wave cursors
    __shared__ int wt2[2];
    __shared__ unsigned ed[LDSE];    // 12 KB staging (compressed records)
    const int tid = threadIdx.x;
    const int w   = tid >> 6;        // wave id 0..7
    const int b   = blockIdx.x;
    const int s   = bucketbase[b];
    const int e   = bucketbase[b + 1];
    const int tot = e - s;

    // fused cvt: this bucket's 128 rows = 2048 float2 words
    #pragma unroll
    for (int k = 0; k < 4; k++) {
        int j = b * 2048 + k * 512 + tid;
        if (j < NN * 16) {
            float2 f = xin2[j];
            hb0[j] = f2bf(f.x) | (f2bf(f.y) << 16);
        }
    }

    for (int k = tid; k < 8 * BROWS; k += 512) (&cntw[0][0])[k] = 0;
    __syncthreads();

    int2 rc[6];
    #pragma unroll
    for (int k = 0; k < 6; k++) {
        int j = s + k * 512 + tid;
        rc[k] = (j < e && j < s + LDSE) ? tmp[j] : make_int2(-1, 0);
        if (rc[k].x >= 0) atomicAdd(&cntw[w][rc[k].x >> 17], 1);
    }
    if (tot > LDSE)                                        // fallback count
        for (int j = s + LDSE + tid; j < e; j += 512)
            atomicAdd(&cntw[w][tmp[j].x >> 17], 1);
    __syncthreads();

    // deg per row, block-exclusive scan -> per-wave cursors + row_ptr
    int v = 0, x = 0;
    if (tid < BROWS) {
        int d = 0;
        #pragma unroll
        for (int ww = 0; ww < 8; ww++) d += cntw[ww][tid];
        v = d;
        int lane = tid & 63;
        x = v;
        #pragma unroll
        for (int off = 1; off < 64; off <<= 1) {
            int y = __shfl_up(x, off, 64);
            if (lane >= off) x += y;
        }
        if (lane == 63) wt2[tid >> 6] = x;
    }
    __syncthreads();
    if (tid < BROWS) {
        int excl = x + ((tid >> 6) ? wt2[0] : 0) - v;
        int r = b * BROWS + tid;
        if (r < NN) row_ptr[r] = s + excl;
        int run = excl;
        #pragma unroll
        for (int ww = 0; ww < 8; ww++) { curw[ww][tid] = run; run += cntw[ww][tid]; }
    }
    __syncthreads();

    if (tot <= LDSE) {
        #pragma unroll
        for (int k = 0; k < 6; k++) {
            if (rc[k].x >= 0) {
                int pos = atomicAdd(&curw[w][rc[k].x >> 17], 1);
                ed[pos] = ((unsigned)(rc[k].x & 0x1FFFF) << 15)
                        | f2h15(__int_as_float(rc[k].y));
            }
        }
        __syncthreads();
        for (int k = tid; k < tot; k += 512)     // coalesced write-back
            edges[s + k] = ed[k];
    } else {
        // fallback (statistically unreachable: bucket > 3072)
        #pragma unroll
        for (int k = 0; k < 6; k++) {
            if (rc[k].x >= 0) {
                int pos = atomicAdd(&curw[w][rc[k].x >> 17], 1);
                edges[s + pos] = ((unsigned)(rc[k].x & 0x1FFFF) << 15)
                               | f2h15(__int_as_float(rc[k].y));
            }
        }
        for (int j = s + LDSE + tid; j < e; j += 512) {
            int2 rec = tmp[j];
            int pos = atomicAdd(&curw[w][rec.x >> 17], 1);
            edges[s + pos] = ((unsigned)(rec.x & 0x1FFFF) << 15)
                           | f2h15(__int_as_float(rec.y));
        }
    }
}

// ---- SpMM: 4-lane group per row, bf16 gather, software-pipelined ---------
// Lane t in [0,4) owns feats [8t, 8t+8) = one uint4 of the bf16 row.
// Edges are 4 B compressed (col<<15 | fp16 val). Next 8-edge batch is
// preloaded during current batch's gathers+FMA. Epilogue x/out reads
// hoisted to kernel start.
// MODE 0: houtb = bf16(A x)  ; out  = x + A x
// MODE 1: houtb = bf16(A h)  ; out += A h
// MODE 2: out = (out + A h) * 0.25

template <int MODE>
__global__ __launch_bounds__(256) void spmm_kernel(
    const int* __restrict__ row_ptr, const unsigned* __restrict__ edges,
    const uint4* __restrict__ hb4,               // bf16 table, 4 uint4/row
    uint4* __restrict__ houtb4,                  // next bf16 table
    const float4* __restrict__ xin4, float4* __restrict__ out4)
{
    const int g = blockIdx.x * 64 + (threadIdx.x >> 2);   // row
    if (g >= NN) return;
    const int t = threadIdx.x & 3;
    const int s = row_ptr[g];
    const int e = row_ptr[g + 1];
    const int o = g * 8 + t * 2;                 // epilogue float4 index

    // prefetch epilogue inputs (independent of the edge loop)
    float4 p0, p1;
    if (MODE == 0) { p0 = xin4[o]; p1 = xin4[o + 1]; }
    else           { p0 = out4[o]; p1 = out4[o + 1]; }

    float acc[8] = {0.f, 0.f, 0.f, 0.f, 0.f, 0.f, 0.f, 0.f};

#define ACC8(W, V)                                                         \
    do {                                                                   \
        acc[0] += (V) * __uint_as_float((W).x << 16);                      \
        acc[1] += (V) * __uint_as_float((W).x & 0xffff0000u);              \
        acc[2] += (V) * __uint_as_float((W).y << 16);                      \
        acc[3] += (V) * __uint_as_float((W).y & 0xffff0000u);              \
        acc[4] += (V) * __uint_as_float((W).z << 16);                      \
        acc[5] += (V) * __uint_as_float((W).z & 0xffff0000u);              \
        acc[6] += (V) * __uint_as_float((W).w << 16);                      \
        acc[7] += (V) * __uint_as_float((W).w & 0xffff0000u);              \
    } while (0)

    unsigned a0, a1, a2, a3, a4, a5, a6, a7;
    int i = s;
    if (i + 8 <= e) {                            // preload first batch
        a0 = edges[i];     a1 = edges[i + 1];
        a2 = edges[i + 2]; a3 = edges[i + 3];
        a4 = edges[i + 4]; a5 = edges[i + 5];
        a6 = edges[i + 6]; a7 = edges[i + 7];
    }
    for (; i + 16 <= e; i += 8) {                // pipelined main loop
        uint4 w0 = hb4[(a0 >> 15) * 4 + t];
        uint4 w1 = hb4[(a1 >> 15) * 4 + t];
        uint4 w2 = hb4[(a2 >> 15) * 4 + t];
        uint4 w3 = hb4[(a3 >> 15) * 4 + t];
        uint4 w4 = hb4[(a4 >> 15) * 4 + t];
        uint4 w5 = hb4[(a5 >> 15) * 4 + t];
        uint4 w6 = hb4[(a6 >> 15) * 4 + t];
        uint4 w7 = hb4[(a7 >> 15) * 4 + t];
        unsigned b0 = edges[i + 8];  unsigned b1 = edges[i + 9];
        unsigned b2 = edges[i + 10]; unsigned b3 = edges[i + 11];
        unsigned b4 = edges[i + 12]; unsigned b5 = edges[i + 13];
        unsigned b6 = edges[i + 14]; unsigned b7 = edges[i + 15];
        ACC8(w0, h152f(a0)); ACC8(w1, h152f(a1));
        ACC8(w2, h152f(a2)); ACC8(w3, h152f(a3));
        ACC8(w4, h152f(a4)); ACC8(w5, h152f(a5));
        ACC8(w6, h152f(a6)); ACC8(w7, h152f(a7));
        a0 = b0; a1 = b1; a2 = b2; a3 = b3;
        a4 = b4; a5 = b5; a6 = b6; a7 = b7;
    }
    if (i + 8 <= e) {                            // last preloaded batch
        uint4 w0 = hb4[(a0 >> 15) * 4 + t];
        uint4 w1 = hb4[(a1 >> 15) * 4 + t];
        uint4 w2 = hb4[(a2 >> 15) * 4 + t];
        uint4 w3 = hb4[(a3 >> 15) * 4 + t];
        uint4 w4 = hb4[(a4 >> 15) * 4 + t];
        uint4 w5 = hb4[(a5 >> 15) * 4 + t];
        uint4 w6 = hb4[(a6 >> 15) * 4 + t];
        uint4 w7 = hb4[(a7 >> 15) * 4 + t];
        ACC8(w0, h152f(a0)); ACC8(w1, h152f(a1));
        ACC8(w2, h152f(a2)); ACC8(w3, h152f(a3));
        ACC8(w4, h152f(a4)); ACC8(w5, h152f(a5));
        ACC8(w6, h152f(a6)); ACC8(w7, h152f(a7));
        i += 8;
    }
    for (; i + 4 <= e; i += 4) {
        unsigned c0 = edges[i];
        unsigned c1 = edges[i + 1];
        unsigned c2 = edges[i + 2];
        unsigned c3 = edges[i + 3];
        uint4 w0 = hb4[(c0 >> 15) * 4 + t];
        uint4 w1 = hb4[(c1 >> 15) * 4 + t];
        uint4 w2 = hb4[(c2 >> 15) * 4 + t];
        uint4 w3 = hb4[(c3 >> 15) * 4 + t];
        ACC8(w0, h152f(c0)); ACC8(w1, h152f(c1));
        ACC8(w2, h152f(c2)); ACC8(w3, h152f(c3));
    }
    for (; i < e; ++i) {
        unsigned c0 = edges[i];
        uint4 w0 = hb4[(c0 >> 15) * 4 + t];
        ACC8(w0, h152f(c0));
    }
#undef ACC8

    // epilogue: lane owns feats [8t, 8t+8)
    if (MODE == 0 || MODE == 1) {
        uint4 p;
        p.x = f2bf(acc[0]) | (f2bf(acc[1]) << 16);
        p.y = f2bf(acc[2]) | (f2bf(acc[3]) << 16);
        p.z = f2bf(acc[4]) | (f2bf(acc[5]) << 16);
        p.w = f2bf(acc[6]) | (f2bf(acc[7]) << 16);
        houtb4[g * 4 + t] = p;
    }
    float4 lo, hi;
    if (MODE == 0 || MODE == 1) {
        lo = make_float4(p0.x + acc[0], p0.y + acc[1], p0.z + acc[2], p0.w + acc[3]);
        hi = make_float4(p1.x + acc[4], p1.y + acc[5], p1.z + acc[6], p1.w + acc[7]);
    } else {
        lo = make_float4((p0.x + acc[0]) * 0.25f, (p0.y + acc[1]) * 0.25f,
                         (p0.z + acc[2]) * 0.25f, (p0.w + acc[3]) * 0.25f);
        hi = make_float4((p1.x + acc[4]) * 0.25f, (p1.y + acc[5]) * 0.25f,
                         (p1.z + acc[6]) * 0.25f, (p1.w + acc[7]) * 0.25f);
    }
    out4[o] = lo;
    out4[o + 1] = hi;
}

// ---- launch ---------------------------------------------------------------

extern "C" void kernel_launch(void* const* d_in, const int* in_sizes, int n_in,
                              void* d_out, int out_size, void* d_ws, size_t ws_size,
                              hipStream_t stream) {
    const int*   edge_row = (const int*)d_in[0];
    const int*   edge_col = (const int*)d_in[1];
    const float* edge_val = (const float*)d_in[2];
    const float* x        = (const float*)d_in[3];
    float* out = (float*)d_out;

    char* ws = (char*)d_ws;
    int*  H          = (int*)ws;   ws += (((size_t)NCHUNK * NBKT * 4) + 511) & ~511ull; // 1.22 MB
    int*  Pt         = (int*)ws;   ws += (((size_t)NBKT * NCHUNK * 4) + 511) & ~511ull; // 1.22 MB
    int*  tot        = (int*)ws;   ws += 4096;
    int*  bucketbase = (int*)ws;   ws += 4096;
    int*  row_ptr    = (int*)ws;   ws += ((size_t)(NN + 1) * 4 + 511) & ~511ull;
    int2* tmp        = (int2*)ws;  ws += (size_t)NE * 8 + 64;   // 12.8 MB
    unsigned* edges  = (unsigned*)ws; ws += (size_t)NE * 4 + 64; // 6.4 MB compressed
    unsigned* hb0    = (unsigned*)ws;  ws += (size_t)NN * DD * 2;  // 6.4 MB bf16
    unsigned* hb1    = (unsigned*)ws;  ws += (size_t)NN * DD * 2;  // 6.4 MB bf16

    hist_kernel        <<<NCHUNK, 1024, 0, stream>>>(edge_row, H);
    scan_tr_kernel     <<<(NBKT + 15) / 16, 1024, 0, stream>>>(H, Pt, tot);
    scan_buckets_kernel<<<1, 1024, 0, stream>>>(tot, bucketbase, row_ptr);
    scatter_kernel     <<<NCHUNK, 1024, 0, stream>>>(edge_row, edge_col, edge_val,
                                                     bucketbase, Pt, tmp);
    bucket_sort_kernel <<<NBKT, 512, 0, stream>>>(bucketbase, tmp, row_ptr, edges,
                                                  (const float2*)x, hb0);

    dim3 sp_grid((NN + 63) / 64);   // 1563 blocks, 4 lanes/row, 64 rows/block
    spmm_kernel<0><<<sp_grid, 256, 0, stream>>>(row_ptr, edges,
        (const uint4*)hb0, (uint4*)hb1, (const float4*)x, (float4*)out);
    spmm_kernel<1><<<sp_grid, 256, 0, stream>>>(row_ptr, edges,
        (const uint4*)hb1, (uint4*)hb0, (const float4*)x, (float4*)out);
    spmm_kernel<2><<<sp_grid, 256, 0, stream>>>(row_ptr, edges,
        (const uint4*)hb0, (uint4*)hb1, (const float4*)x, (float4*)out);
}

// Round 11
// 174.266 us; speedup vs baseline: 1.3188x; 1.0358x over previous
//
#include <hip/hip_runtime.h>
#include <hip/hip_fp16.h>

// LightGCN propagation on MI355X (gfx950).
//   h_{k+1}[r,:] = sum_{e: row[e]==r} val[e] * h_k[col[e],:]   D=32
//   out = (x + h1 + h2 + h3) / 4
//
// Round 20: R19 confirmed (180.5, best-ever; edge compression worked ->
// stream-bytes model holds). This round cuts the remaining fat streams:
//  * fp32 `out` running accumulator DELETED. Mid layers write only their
//    bf16 tables (h1b, h2b) -- no fp32 epilogue. Final layer computes
//    out = (x + h1b + h2b + h3)*0.25 reading the two bf16 tables per-row
//    (sequential, coalesced). Saves 38.4 MB of L2/HBM streams; extra
//    error from bf16-rounded h1,h2 ~ 0.01 abs (absmax 0.125 -> ~0.13,
//    threshold 0.4).
//  * scan_buckets dispatch deleted: scatter dual-scans (cnt, tot) in one
//    interleaved shfl pass to get bucketbase locally; block 0 materializes
//    bucketbase[] for bucket_sort; bucket_sort writes row_ptr[NN] via
//    r <= NN (last bucket's rows >= NN have zero edges -> prefix == NE).
// Everything else (compressed 4 B edges, spmm pipeline, fused cvt,
// wave-privatized bucket_sort) unchanged from R19.

#define NN 100000
#define NE 1600000
#define DD 32
#define CHUNK 4096
#define NCHUNK ((NE + CHUNK - 1) / CHUNK)   // 391
#define BROWS 128
#define NBKT ((NN + BROWS - 1) / BROWS)     // 782
#define LDSE 3072                           // LDS staging cap in bucket_sort

__device__ __forceinline__ unsigned f2bf(float f) {
    unsigned u = __float_as_uint(f);
    return (u + 0x7fffu + ((u >> 16) & 1u)) >> 16;   // RNE
}

// val (>=0) -> 15-bit fp16 payload
__device__ __forceinline__ unsigned f2h15(float v) {
    return (unsigned)__half_as_ushort(__float2half(v)) & 0x7fffu;
}
// 15-bit fp16 payload -> float
__device__ __forceinline__ float h152f(unsigned u) {
    return __half2float(__ushort_as_half((unsigned short)(u & 0x7fffu)));
}

#define BF_LO(u) __uint_as_float((u) << 16)
#define BF_HI(u) __uint_as_float((u) & 0xffff0000u)

// ---- pass 1: per-chunk bucket histogram matrix H[c][b] (coalesced) -------

__global__ __launch_bounds__(1024) void hist_kernel(
    const int* __restrict__ row, int* __restrict__ H)
{
    __shared__ int cnt[NBKT];
    const int tid = threadIdx.x;
    const int start = blockIdx.x * CHUNK;
    const int n = min(CHUNK, NE - start);
    for (int k = tid; k < NBKT; k += 1024) cnt[k] = 0;
    __syncthreads();
    const int j = tid * 4;                       // 4 edges per thread
    if (j + 3 < n) {
        int4 r4 = *(const int4*)(row + start + j);
        atomicAdd(&cnt[r4.x >> 7], 1);
        atomicAdd(&cnt[r4.y >> 7], 1);
        atomicAdd(&cnt[r4.z >> 7], 1);
        atomicAdd(&cnt[r4.w >> 7], 1);
    } else {
        for (int k = j; k < n; k++) atomicAdd(&cnt[row[start + k] >> 7], 1);
    }
    __syncthreads();
    int* Hrow = H + (size_t)blockIdx.x * NBKT;
    for (int k = tid; k < NBKT; k += 1024) Hrow[k] = cnt[k];   // coalesced
}

// ---- pass 2: wave-parallel per-bucket scan over chunks -------------------

__global__ __launch_bounds__(1024) void scan_tr_kernel(
    const int* __restrict__ H, int* __restrict__ Pt, int* __restrict__ tot)
{
    const int b = blockIdx.x * 16 + (threadIdx.x >> 6);
    if (b >= NBKT) return;
    const int lane = threadIdx.x & 63;
    int run = 0;
    #pragma unroll
    for (int c0 = 0; c0 < NCHUNK; c0 += 64) {
        int c = c0 + lane;
        int v = (c < NCHUNK) ? H[(size_t)c * NBKT + b] : 0;
        int x = v;
        #pragma unroll
        for (int off = 1; off < 64; off <<= 1) {
            int y = __shfl_up(x, off, 64);
            if (lane >= off) x += y;
        }
        if (c < NCHUNK) Pt[(size_t)b * NCHUNK + c] = run + x - v;  // exclusive
        run += __shfl(x, 63, 64);                 // wave total
    }
    if (lane == 0) tot[b] = run;
}

// ---- pass 3: multisplit scatter; dual scan (cnt, tot) -> lbase+bucketbase
// record: ((row & 127) << 17) | col   (col < 2^17), val bits in .y

__global__ __launch_bounds__(1024) void scatter_kernel(
    const int* __restrict__ row, const int* __restrict__ col,
    const float* __restrict__ val, const int* __restrict__ tot,
    const int* __restrict__ Pt, int2* __restrict__ tmp,
    int* __restrict__ bucketbase_g)
{
    __shared__ int cnt[NBKT];      // 3.1 KB
    __shared__ int lbase[NBKT];    // 3.1 KB  chunk-local exclusive scan
    __shared__ int gofs[NBKT];     // 3.1 KB  global base per bucket
    __shared__ int wtA[16], wtB[16];
    __shared__ int2 recs[CHUNK];   // 32 KB   records in bucket order
    __shared__ int dest[CHUNK];    // 16 KB   global dst per sorted position
    const int tid = threadIdx.x;
    const int start = blockIdx.x * CHUNK;
    const int n = min(CHUNK, NE - start);
    for (int k = tid; k < NBKT; k += 1024) cnt[k] = 0;
    __syncthreads();

    int rrow[CHUNK / 1024], rcol[CHUNK / 1024], rank[CHUNK / 1024];
    float rval[CHUNK / 1024];
    #pragma unroll
    for (int k = 0; k < CHUNK / 1024; k++) {
        int j = k * 1024 + tid;
        if (j < n) {
            int r = row[start + j];
            rrow[k] = r;
            rcol[k] = col[start + j];
            rval[k] = val[start + j];
            rank[k] = atomicAdd(&cnt[r >> 7], 1);
        } else {
            rrow[k] = -1;
        }
    }
    __syncthreads();

    // dual block-exclusive scan: cnt -> lbase ; tot -> bucketbase
    int v1 = (tid < NBKT) ? cnt[tid] : 0;
    int v2 = (tid < NBKT) ? tot[tid] : 0;
    {
        int lane = tid & 63, w = tid >> 6;
        int x1 = v1, x2 = v2;
        #pragma unroll
        for (int off = 1; off < 64; off <<= 1) {
            int y1 = __shfl_up(x1, off, 64);
            int y2 = __shfl_up(x2, off, 64);
            if (lane >= off) { x1 += y1; x2 += y2; }
        }
        if (lane == 63) { wtA[w] = x1; wtB[w] = x2; }
        __syncthreads();
        if (w == 0 && lane < 16) {
            int y1 = wtA[lane], y2 = wtB[lane];
            #pragma unroll
            for (int off = 1; off < 16; off <<= 1) {
                int z1 = __shfl_up(y1, off, 16);
                int z2 = __shfl_up(y2, off, 16);
                if ((lane & 15) >= off) { y1 += z1; y2 += z2; }
            }
            wtA[lane] = y1; wtB[lane] = y2;
        }
        __syncthreads();
        int e1 = x1 + ((w > 0) ? wtA[w - 1] : 0) - v1;
        int e2 = x2 + ((w > 0) ? wtB[w - 1] : 0) - v2;
        if (tid < NBKT) {
            lbase[tid] = e1;
            gofs[tid] = e2 + Pt[(size_t)tid * NCHUNK + blockIdx.x];
            if (blockIdx.x == 0) bucketbase_g[tid] = e2;
        }
        if (blockIdx.x == 0 && tid == NBKT) bucketbase_g[NBKT] = NE;
    }
    __syncthreads();

    #pragma unroll
    for (int k = 0; k < CHUNK / 1024; k++) {
        if (rrow[k] >= 0) {
            int b = rrow[k] >> 7;
            int p = lbase[b] + rank[k];
            recs[p] = make_int2(((rrow[k] & 127) << 17) | rcol[k],
                                __float_as_int(rval[k]));
            dest[p] = gofs[b] + rank[k];
        }
    }
    __syncthreads();

    for (int p = tid; p < n; p += 1024)        // run-contiguous stores
        tmp[dest[p]] = recs[p];
}

// ---- pass 4: per-bucket row sort (wave-privatized) + fused cvt -----------
// Emits COMPRESSED edges: u32 = (col << 15) | fp16bits(val)  (val >= 0).
// Block b also converts x rows [b*128, b*128+128) to the bf16 table.
// Writes row_ptr for r <= NN (covers row_ptr[NN] = NE).

__global__ __launch_bounds__(512) void bucket_sort_kernel(
    const int* __restrict__ bucketbase, const int2* __restrict__ tmp,
    int* __restrict__ row_ptr, unsigned* __restrict__ edges,
    const float2* __restrict__ xin2, unsigned* __restrict__ hb0)
{
    __shared__ int cntw[8][BROWS];   // 4 KB  per-wave counts
    __shared__ int curw[8][BROWS];   // 4 KB  per-wave cursors
    __shared__ int wt2[2];
    __shared__ unsigned ed[LDSE];    // 12 KB staging (compressed records)
    const int tid = threadIdx.x;
    const int w   = tid >> 6;        // wave id 0..7
    const int b   = blockIdx.x;
    const int s   = bucketbase[b];
    const int e   = bucketbase[b + 1];
    const int tot = e - s;

    // fused cvt: this bucket's 128 rows = 2048 float2 words
    #pragma unroll
    for (int k = 0; k < 4; k++) {
        int j = b * 2048 + k * 512 + tid;
        if (j < NN * 16) {
            float2 f = xin2[j];
            hb0[j] = f2bf(f.x) | (f2bf(f.y) << 16);
        }
    }

    for (int k = tid; k < 8 * BROWS; k += 512) (&cntw[0][0])[k] = 0;
    __syncthreads();

    int2 rc[6];
    #pragma unroll
    for (int k = 0; k < 6; k++) {
        int j = s + k * 512 + tid;
        rc[k] = (j < e && j < s + LDSE) ? tmp[j] : make_int2(-1, 0);
        if (rc[k].x >= 0) atomicAdd(&cntw[w][rc[k].x >> 17], 1);
    }
    if (tot > LDSE)                                        // fallback count
        for (int j = s + LDSE + tid; j < e; j += 512)
            atomicAdd(&cntw[w][tmp[j].x >> 17], 1);
    __syncthreads();

    // deg per row, block-exclusive scan -> per-wave cursors + row_ptr
    int v = 0, x = 0;
    if (tid < BROWS) {
        int d = 0;
        #pragma unroll
        for (int ww = 0; ww < 8; ww++) d += cntw[ww][tid];
        v = d;
        int lane = tid & 63;
        x = v;
        #pragma unroll
        for (int off = 1; off < 64; off <<= 1) {
            int y = __shfl_up(x, off, 64);
            if (lane >= off) x += y;
        }
        if (lane == 63) wt2[tid >> 6] = x;
    }
    __syncthreads();
    if (tid < BROWS) {
        int excl = x + ((tid >> 6) ? wt2[0] : 0) - v;
        int r = b * BROWS + tid;
        if (r <= NN) row_ptr[r] = s + excl;      // r==NN -> NE (last bucket)
        int run = excl;
        #pragma unroll
        for (int ww = 0; ww < 8; ww++) { curw[ww][tid] = run; run += cntw[ww][tid]; }
    }
    __syncthreads();

    if (tot <= LDSE) {
        #pragma unroll
        for (int k = 0; k < 6; k++) {
            if (rc[k].x >= 0) {
                int pos = atomicAdd(&curw[w][rc[k].x >> 17], 1);
                ed[pos] = ((unsigned)(rc[k].x & 0x1FFFF) << 15)
                        | f2h15(__int_as_float(rc[k].y));
            }
        }
        __syncthreads();
        for (int k = tid; k < tot; k += 512)     // coalesced write-back
            edges[s + k] = ed[k];
    } else {
        // fallback (statistically unreachable: bucket > 3072)
        #pragma unroll
        for (int k = 0; k < 6; k++) {
            if (rc[k].x >= 0) {
                int pos = atomicAdd(&curw[w][rc[k].x >> 17], 1);
                edges[s + pos] = ((unsigned)(rc[k].x & 0x1FFFF) << 15)
                               | f2h15(__int_as_float(rc[k].y));
            }
        }
        for (int j = s + LDSE + tid; j < e; j += 512) {
            int2 rec = tmp[j];
            int pos = atomicAdd(&curw[w][rec.x >> 17], 1);
            edges[s + pos] = ((unsigned)(rec.x & 0x1FFFF) << 15)
                           | f2h15(__int_as_float(rec.y));
        }
    }
}

// ---- SpMM: 4-lane group per row, bf16 gather, software-pipelined ---------
// Lane t in [0,4) owns feats [8t, 8t+8). Edges are 4 B compressed
// (col<<15 | fp16 val). Next 8-edge batch preloaded during current batch.
// FINAL==0: houtb = bf16(A h)                      (mid layers 1,2)
// FINAL==1: out = (x + h1b + h2b + A h2) * 0.25    (h1b4 = h1 table rows)

template <int FINAL>
__global__ __launch_bounds__(256) void spmm_kernel(
    const int* __restrict__ row_ptr, const unsigned* __restrict__ edges,
    const uint4* __restrict__ hb4,               // gather table (4 uint4/row)
    uint4* __restrict__ houtb4,                  // next bf16 table (mid)
    const uint4* __restrict__ h1b4,              // h1 table rows (final)
    const float4* __restrict__ xin4, float4* __restrict__ out4)
{
    const int g = blockIdx.x * 64 + (threadIdx.x >> 2);   // row
    if (g >= NN) return;
    const int t = threadIdx.x & 3;
    const int s = row_ptr[g];
    const int e = row_ptr[g + 1];
    const int o = g * 8 + t * 2;                 // epilogue float4 index

    // prefetch epilogue inputs (independent of the edge loop)
    float4 p0, p1; uint4 q1, q2;
    if (FINAL) {
        p0 = xin4[o]; p1 = xin4[o + 1];
        q1 = h1b4[g * 4 + t];                    // h1 bf16 row chunk
        q2 = hb4[g * 4 + t];                     // h2 bf16 row chunk
    }

    float acc[8] = {0.f, 0.f, 0.f, 0.f, 0.f, 0.f, 0.f, 0.f};

#define ACC8(W, V)                                                         \
    do {                                                                   \
        acc[0] += (V) * BF_LO((W).x);                                      \
        acc[1] += (V) * BF_HI((W).x);                                      \
        acc[2] += (V) * BF_LO((W).y);                                      \
        acc[3] += (V) * BF_HI((W).y);                                      \
        acc[4] += (V) * BF_LO((W).z);                                      \
        acc[5] += (V) * BF_HI((W).z);                                      \
        acc[6] += (V) * BF_LO((W).w);                                      \
        acc[7] += (V) * BF_HI((W).w);                                      \
    } while (0)

    unsigned a0, a1, a2, a3, a4, a5, a6, a7;
    int i = s;
    if (i + 8 <= e) {                            // preload first batch
        a0 = edges[i];     a1 = edges[i + 1];
        a2 = edges[i + 2]; a3 = edges[i + 3];
        a4 = edges[i + 4]; a5 = edges[i + 5];
        a6 = edges[i + 6]; a7 = edges[i + 7];
    }
    for (; i + 16 <= e; i += 8) {                // pipelined main loop
        uint4 w0 = hb4[(a0 >> 15) * 4 + t];
        uint4 w1 = hb4[(a1 >> 15) * 4 + t];
        uint4 w2 = hb4[(a2 >> 15) * 4 + t];
        uint4 w3 = hb4[(a3 >> 15) * 4 + t];
        uint4 w4 = hb4[(a4 >> 15) * 4 + t];
        uint4 w5 = hb4[(a5 >> 15) * 4 + t];
        uint4 w6 = hb4[(a6 >> 15) * 4 + t];
        uint4 w7 = hb4[(a7 >> 15) * 4 + t];
        unsigned b0 = edges[i + 8];  unsigned b1 = edges[i + 9];
        unsigned b2 = edges[i + 10]; unsigned b3 = edges[i + 11];
        unsigned b4 = edges[i + 12]; unsigned b5 = edges[i + 13];
        unsigned b6 = edges[i + 14]; unsigned b7 = edges[i + 15];
        ACC8(w0, h152f(a0)); ACC8(w1, h152f(a1));
        ACC8(w2, h152f(a2)); ACC8(w3, h152f(a3));
        ACC8(w4, h152f(a4)); ACC8(w5, h152f(a5));
        ACC8(w6, h152f(a6)); ACC8(w7, h152f(a7));
        a0 = b0; a1 = b1; a2 = b2; a3 = b3;
        a4 = b4; a5 = b5; a6 = b6; a7 = b7;
    }
    if (i + 8 <= e) {                            // last preloaded batch
        uint4 w0 = hb4[(a0 >> 15) * 4 + t];
        uint4 w1 = hb4[(a1 >> 15) * 4 + t];
        uint4 w2 = hb4[(a2 >> 15) * 4 + t];
        uint4 w3 = hb4[(a3 >> 15) * 4 + t];
        uint4 w4 = hb4[(a4 >> 15) * 4 + t];
        uint4 w5 = hb4[(a5 >> 15) * 4 + t];
        uint4 w6 = hb4[(a6 >> 15) * 4 + t];
        uint4 w7 = hb4[(a7 >> 15) * 4 + t];
        ACC8(w0, h152f(a0)); ACC8(w1, h152f(a1));
        ACC8(w2, h152f(a2)); ACC8(w3, h152f(a3));
        ACC8(w4, h152f(a4)); ACC8(w5, h152f(a5));
        ACC8(w6, h152f(a6)); ACC8(w7, h152f(a7));
        i += 8;
    }
    for (; i + 4 <= e; i += 4) {
        unsigned c0 = edges[i];
        unsigned c1 = edges[i + 1];
        unsigned c2 = edges[i + 2];
        unsigned c3 = edges[i + 3];
        uint4 w0 = hb4[(c0 >> 15) * 4 + t];
        uint4 w1 = hb4[(c1 >> 15) * 4 + t];
        uint4 w2 = hb4[(c2 >> 15) * 4 + t];
        uint4 w3 = hb4[(c3 >> 15) * 4 + t];
        ACC8(w0, h152f(c0)); ACC8(w1, h152f(c1));
        ACC8(w2, h152f(c2)); ACC8(w3, h152f(c3));
    }
    for (; i < e; ++i) {
        unsigned c0 = edges[i];
        uint4 w0 = hb4[(c0 >> 15) * 4 + t];
        ACC8(w0, h152f(c0));
    }
#undef ACC8

    if (!FINAL) {
        // mid layer: write next bf16 table only
        uint4 p;
        p.x = f2bf(acc[0]) | (f2bf(acc[1]) << 16);
        p.y = f2bf(acc[2]) | (f2bf(acc[3]) << 16);
        p.z = f2bf(acc[4]) | (f2bf(acc[5]) << 16);
        p.w = f2bf(acc[6]) | (f2bf(acc[7]) << 16);
        houtb4[g * 4 + t] = p;
    } else {
        // final: out = (x + h1b + h2b + acc) * 0.25
        float4 lo, hi;
        lo.x = (p0.x + BF_LO(q1.x) + BF_LO(q2.x) + acc[0]) * 0.25f;
        lo.y = (p0.y + BF_HI(q1.x) + BF_HI(q2.x) + acc[1]) * 0.25f;
        lo.z = (p0.z + BF_LO(q1.y) + BF_LO(q2.y) + acc[2]) * 0.25f;
        lo.w = (p0.w + BF_HI(q1.y) + BF_HI(q2.y) + acc[3]) * 0.25f;
        hi.x = (p1.x + BF_LO(q1.z) + BF_LO(q2.z) + acc[4]) * 0.25f;
        hi.y = (p1.y + BF_HI(q1.z) + BF_HI(q2.z) + acc[5]) * 0.25f;
        hi.z = (p1.z + BF_LO(q1.w) + BF_LO(q2.w) + acc[6]) * 0.25f;
        hi.w = (p1.w + BF_HI(q1.w) + BF_HI(q2.w) + acc[7]) * 0.25f;
        out4[o] = lo;
        out4[o + 1] = hi;
    }
}

// ---- launch ---------------------------------------------------------------

extern "C" void kernel_launch(void* const* d_in, const int* in_sizes, int n_in,
                              void* d_out, int out_size, void* d_ws, size_t ws_size,
                              hipStream_t stream) {
    const int*   edge_row = (const int*)d_in[0];
    const int*   edge_col = (const int*)d_in[1];
    const float* edge_val = (const float*)d_in[2];
    const float* x        = (const float*)d_in[3];
    float* out = (float*)d_out;

    char* ws = (char*)d_ws;
    int*  H          = (int*)ws;   ws += (((size_t)NCHUNK * NBKT * 4) + 511) & ~511ull; // 1.22 MB
    int*  Pt         = (int*)ws;   ws += (((size_t)NBKT * NCHUNK * 4) + 511) & ~511ull; // 1.22 MB
    int*  tot        = (int*)ws;   ws += 4096;
    int*  bucketbase = (int*)ws;   ws += 4096;
    int*  row_ptr    = (int*)ws;   ws += ((size_t)(NN + 1) * 4 + 511) & ~511ull;
    int2* tmp        = (int2*)ws;  ws += (size_t)NE * 8 + 64;   // 12.8 MB
    unsigned* edges  = (unsigned*)ws; ws += (size_t)NE * 4 + 64; // 6.4 MB compressed
    unsigned* hb0    = (unsigned*)ws;  ws += (size_t)NN * DD * 2;  // 6.4 MB bf16
    unsigned* hb1    = (unsigned*)ws;  ws += (size_t)NN * DD * 2;  // 6.4 MB bf16
    unsigned* hb2    = (unsigned*)ws;  ws += (size_t)NN * DD * 2;  // 6.4 MB bf16

    hist_kernel       <<<NCHUNK, 1024, 0, stream>>>(edge_row, H);
    scan_tr_kernel    <<<(NBKT + 15) / 16, 1024, 0, stream>>>(H, Pt, tot);
    scatter_kernel    <<<NCHUNK, 1024, 0, stream>>>(edge_row, edge_col, edge_val,
                                                    tot, Pt, tmp, bucketbase);
    bucket_sort_kernel<<<NBKT, 512, 0, stream>>>(bucketbase, tmp, row_ptr, edges,
                                                 (const float2*)x, hb0);

    dim3 sp_grid((NN + 63) / 64);   // 1563 blocks, 4 lanes/row, 64 rows/block
    // layer 1: h1b = bf16(A x)
    spmm_kernel<0><<<sp_grid, 256, 0, stream>>>(row_ptr, edges,
        (const uint4*)hb0, (uint4*)hb1, nullptr, nullptr, nullptr);
    // layer 2: h2b = bf16(A h1)
    spmm_kernel<0><<<sp_grid, 256, 0, stream>>>(row_ptr, edges,
        (const uint4*)hb1, (uint4*)hb2, nullptr, nullptr, nullptr);
    // layer 3: out = (x + h1b + h2b + A h2) / 4
    spmm_kernel<1><<<sp_grid, 256, 0, stream>>>(row_ptr, edges,
        (const uint4*)hb2, nullptr, (const uint4*)hb1,
        (const float4*)x, (float4*)out);
}